// Round 11
// baseline (48.469 us; speedup 1.0000x reference)
//
#include <hip/hip_runtime.h>

// NCuts loss: seg [8,4,224,224], padded_seg [8,4,232,232],
// weight [8,1,224,224,9,9], sum_weight [8,1,224,224] -> out[8] (fp32)
//
// stage1: persistent blocks, grid = 256 = #CUs (LDS 105KB -> 1 block/CU).
// Block owns 7 consecutive rows. Counted-vmcnt pipeline (T3/T4):
//  - psg: all 15 needed padded rows ([15][4][232], 55.7KB) staged ONCE in
//    the prologue via global_load_lds. seg is read from this window
//    (seg[c,h,w] == padded_seg[c,h+4,w+4]); sum_weight is recomputed as
//    sum of the 81 staged weights -> the main loop issues NO global loads
//    except the weight DMA, so vmcnt counts are exact and wave-uniform.
//  - weight: 28 tiles (56px*81), double-buffered global_load_lds, each wave
//    issues EXACTLY 3 GLL16/tile (slab padded to 1536 f4, clamped source).
//    Loop: {issue next(3/wave); s_waitcnt vmcnt(3); s_barrier; compute;
//    s_barrier} -- prefetch stays in flight ACROSS barriers (never
//    vmcnt(0) mid-loop), unlike __syncthreads which drains it.
//  - tap loop: 81 taps over 8 waves, compile-time indices, b32 reads
//    (lane-stride 1 / 17 dwords -> conflict-free), register rA/rV fold,
//    single block-end reduction.

constexpr int NN  = 8;
constexpr int KK  = 4;
constexpr int HH  = 224;
constexpr int WW  = 224;
constexpr int PAD = 4;                   // RADIUS-1
constexpr int HP  = HH + 2 * PAD;        // 232
constexpr int WP  = WW + 2 * PAD;        // 232
constexpr int NWIN = 81;
constexpr int PIX = HH * WW;             // 50176
constexpr int TPB = 512;                 // 8 waves
constexpr int PPB = 56;                  // pixels per tile
constexpr int TPR = WW / PPB;            // 4 tiles per row
constexpr int RPB = 7;                   // rows per block
constexpr int GPI = HH / RPB;            // 32 row-groups per image
constexpr int NBLK = NN * GPI;           // 256 blocks == #CUs
constexpr int PLANE = HP * WP;           // 53824
constexpr int ROWF = KK * WP;            // 928 floats per psg row-slot
constexpr int ROWF4 = ROWF / 4;          // 232
constexpr int NSLOT = RPB + 8;           // 15 padded rows needed
constexpr int PSGALL4 = NSLOT * ROWF4;   // 3480 f4
constexpr int WSLAB = PPB * NWIN;        // 4536 floats per weight tile
constexpr int WF4 = WSLAB / 4;           // 1134 f4 real
constexpr int WPAD4 = 3 * TPB;           // 1536 f4 padded (uniform 3/wave)
constexpr int WPADF = WPAD4 * 4;         // 6144 floats per buffer
constexpr int NTILE = RPB * TPR;         // 28 weight tiles per block

#define GLL16(gptr, lptr)                                            \
    __builtin_amdgcn_global_load_lds(                                \
        (const __attribute__((address_space(1))) void*)(gptr),       \
        (__attribute__((address_space(3))) void*)(lptr), 16, 0, 0)

template<int T0, int T1>
__device__ inline void do_taps(const float* __restrict__ lwp,
                               const float* __restrict__ psg,
                               int sbase, float acc[KK], float& wsum) {
#pragma unroll
    for (int t = T0; t < T1; ++t) {
        const int m = t / 9;
        const int j = t - 9 * m;          // compile-time after unroll
        const float wv = lwp[t];          // ds_read_b32, immediate offset
        wsum += wv;
#pragma unroll
        for (int c = 0; c < KK; ++c)
            acc[c] += psg[sbase + m * ROWF + c * WP + j] * wv;
    }
}

__global__ __launch_bounds__(TPB) void ncuts_stage1(
    const float* __restrict__ seg, const float* __restrict__ pseg,
    const float* __restrict__ wgt, const float* __restrict__ swgt,
    float* __restrict__ part)
{
    const int b    = blockIdx.x;             // n*32 + row-group
    const int n    = b >> 5;
    const int h0   = (b & 31) * RPB;         // first image row of this block
    const int tid  = threadIdx.x;
    const int wv_  = tid >> 6;               // 0..7
    const int lane = tid & 63;

    __shared__ float lds_w[2 * WPADF];       // 49152 B (padded double buffer)
    __shared__ float psg_lds[NSLOT * ROWF];  // 55680 B (15 padded rows)
    __shared__ float lred[8][8];             // 256 B -> 105088 B total

    const size_t nb = (size_t)n * KK * PLANE;
    const float* wbase = wgt + ((size_t)n * PIX + (size_t)h0 * WW) * NWIN;

    // ---- weight tile stager: EXACTLY 3 GLL16 per wave (uniform vmcnt) ----
    auto stage_w = [&](int buf, int ti) {
        const float4* wsrc = (const float4*)(wbase + (size_t)ti * WSLAB);
        float* base = lds_w + buf * WPADF;
#pragma unroll
        for (int k = 0; k < 3; ++k) {
            const int i  = k * TPB + tid;
            const int is = i < WF4 ? i : WF4 - 1;   // clamp: junk -> pad area
            GLL16(wsrc + is, base + ((k * TPB + (tid & ~63)) << 2));
        }
    };

    stage_w(0, 0);                            // async: weight tile 0

    // ---- prologue: psg padded rows h0..h0+14 -> slots 0..14 ----
#pragma unroll
    for (int k = 0; k < 7; ++k) {            // 7*512 >= 3480
        const int i = k * TPB + tid;
        if (i < PSGALL4) {
            const int slot = i / ROWF4;
            const int rem  = i - slot * ROWF4;
            const int c    = rem / 58;           // 58 = WP/4
            const int c4   = rem - c * 58;
            const float* src = pseg + nb + (size_t)c * PLANE +
                               (size_t)(h0 + slot) * WP + c4 * 4;
            GLL16(src, psg_lds + ((k * TPB + (tid & ~63)) << 2));
        }
    }

    float rA[KK] = {0.f, 0.f, 0.f, 0.f};
    float rV[KK] = {0.f, 0.f, 0.f, 0.f};

    __syncthreads();   // prologue-only full drain: psg + weight tile 0 landed

    int cur = 0;
#pragma unroll 1
    for (int ti = 0; ti < NTILE; ++ti) {
        const int s  = ti >> 2;              // row-step 0..6
        const int tt = ti & 3;               // tile in row

        // ---- issue next tile's DMA (3/wave), then counted wait ----
        if (ti + 1 < NTILE) {
            stage_w(cur ^ 1, ti + 1);
            asm volatile("s_waitcnt vmcnt(3)" ::: "memory");  // tile ti landed
        } else {
            asm volatile("s_waitcnt vmcnt(0)" ::: "memory");  // last tile
        }
        __builtin_amdgcn_s_barrier();        // everyone's tile ti visible

        // ---- compute tile ti from LDS; fold into rA/rV ----
        if (lane < PPB) {
            const int colp  = tt * PPB + lane;       // padded col - 4
            const int sbase = s * ROWF + colp;
            float segv[KK];
#pragma unroll
            for (int c = 0; c < KK; ++c)             // seg = psg interior
                segv[c] = psg_lds[(s + 4) * ROWF + c * WP + colp + 4];
            const float* lwp = lds_w + cur * WPADF + lane * NWIN;
            float acc[KK] = {0.f, 0.f, 0.f, 0.f};
            float wsum = 0.f;
            switch (wv_) {
                case 0:  do_taps<0, 10>(lwp, psg_lds, sbase, acc, wsum); break;
                case 1:  do_taps<10, 20>(lwp, psg_lds, sbase, acc, wsum); break;
                case 2:  do_taps<20, 30>(lwp, psg_lds, sbase, acc, wsum); break;
                case 3:  do_taps<30, 40>(lwp, psg_lds, sbase, acc, wsum); break;
                case 4:  do_taps<40, 50>(lwp, psg_lds, sbase, acc, wsum); break;
                case 5:  do_taps<50, 60>(lwp, psg_lds, sbase, acc, wsum); break;
                case 6:  do_taps<60, 70>(lwp, psg_lds, sbase, acc, wsum); break;
                default: do_taps<70, 81>(lwp, psg_lds, sbase, acc, wsum); break;
            }
#pragma unroll
            for (int c = 0; c < KK; ++c) {
                rA[c] += acc[c] * segv[c];
                rV[c] += wsum   * segv[c];
            }
        }
        __builtin_amdgcn_s_barrier();        // all reads of buf cur done
        cur ^= 1;                            //  -> next iter may overwrite it
    }

    // ---- single block-end reduction ----
    float vals[8] = { rA[0], rA[1], rA[2], rA[3], rV[0], rV[1], rV[2], rV[3] };
#pragma unroll
    for (int i = 0; i < 8; ++i) {
        float v = vals[i];
#pragma unroll
        for (int off = 32; off > 0; off >>= 1) v += __shfl_down(v, off, 64);
        if (lane == 0) lred[wv_][i] = v;
    }
    __syncthreads();
    if (tid < 8) {
        float ssum = 0.f;
#pragma unroll
        for (int w = 0; w < 8; ++w) ssum += lred[w][tid];
        part[(size_t)b * 8 + tid] = ssum;
    }
}

__global__ __launch_bounds__(256) void ncuts_stage2(
    const float* __restrict__ part, float* __restrict__ out)
{
    const int n   = blockIdx.x;
    const int tid = threadIdx.x;

    float vals[8] = {0.f, 0.f, 0.f, 0.f, 0.f, 0.f, 0.f, 0.f};
    for (int bb = tid; bb < GPI; bb += 256) {       // 32 entries per image
        const float* q = part + ((size_t)(n * GPI + bb)) * 8;
#pragma unroll
        for (int i = 0; i < 8; ++i) vals[i] += q[i];
    }

    __shared__ float lred[4][8];
    const int lane = tid & 63;
    const int wv_  = tid >> 6;
#pragma unroll
    for (int i = 0; i < 8; ++i) {
        float v = vals[i];
#pragma unroll
        for (int off = 32; off > 0; off >>= 1) v += __shfl_down(v, off, 64);
        if (lane == 0) lred[wv_][i] = v;
    }
    __syncthreads();
    if (tid == 0) {
        float assoc = 0.f;
#pragma unroll
        for (int k = 0; k < 4; ++k) {
            const float A = lred[0][k] + lred[1][k] + lred[2][k] + lred[3][k];
            const float V = lred[0][4 + k] + lred[1][4 + k] + lred[2][4 + k] + lred[3][4 + k];
            assoc += A / V;
        }
        out[n] = 4.0f - assoc;
    }
}

extern "C" void kernel_launch(void* const* d_in, const int* in_sizes, int n_in,
                              void* d_out, int out_size, void* d_ws, size_t ws_size,
                              hipStream_t stream) {
    const float* seg  = (const float*)d_in[0];
    const float* pseg = (const float*)d_in[1];
    const float* wgt  = (const float*)d_in[2];
    const float* swgt = (const float*)d_in[3];
    float* out  = (float*)d_out;
    float* part = (float*)d_ws;   // 256 blocks * 8 floats = 8192 B

    ncuts_stage1<<<NBLK, TPB, 0, stream>>>(seg, pseg, wgt, swgt, part);
    ncuts_stage2<<<NN, 256, 0, stream>>>(part, out);
}